// Round 5
// baseline (86.964 us; speedup 1.0000x reference)
//
#include <hip/hip_runtime.h>
#include <math.h>

constexpr int H  = 48;
constexpr int W  = 84;
constexpr int HW = H * W;      // 4032
constexpr int C  = 64;
constexpr int CQ = 32;
constexpr int QH = 192;
constexpr int QW = 336;
constexpr int NREF = 3;
constexpr int SLG = 176;       // per-ref logit stride (16B aligned)
constexpr int LGS = 544;       // per-pixel logit stride = 3*176 + 16

typedef short bf16x8 __attribute__((ext_vector_type(8)));
typedef float f32x4  __attribute__((ext_vector_type(4)));

#define DEV __device__ __forceinline__

DEV unsigned short f2bf_rn(float f) {
  unsigned int u = __builtin_bit_cast(unsigned int, f);
  u += 0x7FFFu + ((u >> 16) & 1u);
  return (unsigned short)(u >> 16);
}
DEV float bf2f(unsigned short h) {
  unsigned int u = ((unsigned int)h) << 16;
  return __builtin_bit_cast(float, u);
}

DEV float block_sum(float v, float* red) {
  __syncthreads();
#pragma unroll
  for (int o = 32; o > 0; o >>= 1) v += __shfl_down(v, o, 64);
  if ((threadIdx.x & 63) == 0) red[threadIdx.x >> 6] = v;
  __syncthreads();
  return red[0] + red[1] + red[2] + red[3];
}
DEV float block_max(float v, float* red) {
  __syncthreads();
#pragma unroll
  for (int o = 32; o > 0; o >>= 1) v = fmaxf(v, __shfl_down(v, o, 64));
  if ((threadIdx.x & 63) == 0) red[threadIdx.x >> 6] = v;
  __syncthreads();
  return fmaxf(fmaxf(red[0], red[1]), fmaxf(red[2], red[3]));
}

// y<4: transpose feats to channel-last (fp32 + split-bf16).
// y in 4..6: gather quantized_r[:, :, ::4, ::4] -> bf16 channel-last (LDS-staged).
// y==7: zero the accum buffer.
__global__ __launch_bounds__(256) void k_prep(const float* __restrict__ fr,
                                              const float* __restrict__ ft,
                                              const float* __restrict__ q,
                                              float* __restrict__ frT,
                                              float* __restrict__ ftT,
                                              unsigned short* __restrict__ rbh,
                                              unsigned short* __restrict__ rbl,
                                              unsigned short* __restrict__ tbh,
                                              unsigned short* __restrict__ tbl,
                                              unsigned short* __restrict__ qrb,
                                              float* __restrict__ accum) {
  __shared__ float lds[64][65];
  const int mode = blockIdx.y;
  const int tid = threadIdx.x;

  if (mode < 4) {
    const int r = mode;
    const float* src = (r < NREF) ? (fr + (size_t)r * C * HW) : ft;
    float* dstF          = (r < NREF) ? (frT + (size_t)r * HW * C) : ftT;
    unsigned short* dstH = (r < NREF) ? (rbh + (size_t)r * HW * C) : tbh;
    unsigned short* dstL = (r < NREF) ? (rbl + (size_t)r * HW * C) : tbl;
    const int pb = blockIdx.x * 64;
    const int a = tid & 63, b = tid >> 6;
#pragma unroll
    for (int i = 0; i < 16; i++) {
      int c = i * 4 + b;
      lds[c][a] = src[c * HW + pb + a];
    }
    __syncthreads();
#pragma unroll
    for (int i = 0; i < 16; i++) {
      int p = i * 4 + b;
      float v = lds[a][p];
      int o = (pb + p) * C + a;
      dstF[o] = v;
      unsigned short h = f2bf_rn(v);
      dstH[o] = h;
      dstL[o] = f2bf_rn(v - bf2f(h));
    }
  } else if (mode < 7) {
    const int k = mode - 4;
    const int yq = blockIdx.x;
    if (yq >= H) return;
    unsigned short* qs = (unsigned short*)lds;   // [x][c] = 84*32 shorts
    const int c = tid >> 3, xo = tid & 7;
#pragma unroll
    for (int i = 0; i < 11; i++) {
      const int x = xo + 8 * i;
      if (x < W) {
        const float v = q[((size_t)(k * CQ + c) * QH + yq * 4) * QW + x * 4];
        qs[x * CQ + c] = f2bf_rn(v);
      }
    }
    __syncthreads();
    const unsigned int* qsu = (const unsigned int*)qs;
    unsigned int* dst = (unsigned int*)(qrb + (size_t)k * HW * CQ + (size_t)yq * W * CQ);
    for (int o = tid; o < W * CQ / 2; o += 256) dst[o] = qsu[o];
  } else {
    const int nacc = NREF * HW * 3;
    for (int i = blockIdx.x * 256 + tid; i < nacc; i += 63 * 256) accum[i] = 0.f;
  }
}

DEV f32x4 band_mfma(bf16x8 ah0, bf16x8 ah1, bf16x8 al0, bf16x8 al1,
                    const unsigned short* __restrict__ rH,
                    const unsigned short* __restrict__ rL,
                    int bpix, int fko, bool bv) {
  const bf16x8 zf = {0, 0, 0, 0, 0, 0, 0, 0};
  bf16x8 bh0 = *reinterpret_cast<const bf16x8*>(rH + (size_t)bpix * C + fko);
  bf16x8 bh1 = *reinterpret_cast<const bf16x8*>(rH + (size_t)bpix * C + fko + 32);
  bf16x8 bl0 = *reinterpret_cast<const bf16x8*>(rL + (size_t)bpix * C + fko);
  bf16x8 bl1 = *reinterpret_cast<const bf16x8*>(rL + (size_t)bpix * C + fko + 32);
  if (!bv) { bh0 = zf; bh1 = zf; bl0 = zf; bl1 = zf; }
  f32x4 acc = {0.f, 0.f, 0.f, 0.f};
  acc = __builtin_amdgcn_mfma_f32_16x16x32_bf16(ah0, bh0, acc, 0, 0, 0);
  acc = __builtin_amdgcn_mfma_f32_16x16x32_bf16(ah1, bh1, acc, 0, 0, 0);
  acc = __builtin_amdgcn_mfma_f32_16x16x32_bf16(ah0, bl0, acc, 0, 0, 0);
  acc = __builtin_amdgcn_mfma_f32_16x16x32_bf16(ah1, bl1, acc, 0, 0, 0);
  acc = __builtin_amdgcn_mfma_f32_16x16x32_bf16(al0, bh0, acc, 0, 0, 0);
  acc = __builtin_amdgcn_mfma_f32_16x16x32_bf16(al1, bh1, acc, 0, 0, 0);
  return acc;
}

// Flat grid 3456 = 8 XCD-chunks x 432. Each wave runs TWO independent band-row
// chains (search: p, p+16; unfold: dp, dp+8) for ILP/MLP.
__global__ __launch_bounds__(256) void k_mfma(
    const unsigned short* __restrict__ rbh, const unsigned short* __restrict__ rbl,
    const unsigned short* __restrict__ tbh, const unsigned short* __restrict__ tbl,
    const int* __restrict__ ridx, const int* __restrict__ curp,
    float* __restrict__ accum, float* __restrict__ lg) {
  const int bid = blockIdx.x;
  const int idx = bid >> 3;              // 0..431
  const int ychunk = bid & 7;            // XCD chunk -> 6 consecutive y rows
  const int yloc = idx / 72;
  const int rest = idx - yloc * 72;
  const int zi = rest / 6;               // 0..11
  const int x0i = rest - zi * 6;
  const int y = ychunk * 6 + yloc;
  const int x0 = x0i * 16;
  const int si = zi >> 2, pz = zi & 3;

  const int gap = curp[0] - ridx[si];
  const bool isSearch = gap > 15;
  const int lane = threadIdx.x & 63, wave = threadIdx.x >> 6;
  if (!isSearch && pz >= 2) return;

  const int fpx = lane & 15, fko = (lane >> 4) * 8;
  const bool pValid = (x0 + fpx) < W;
  const int apix = pValid ? (y * W + x0 + fpx) : 0;
  const bf16x8 zf = {0, 0, 0, 0, 0, 0, 0, 0};
  bf16x8 ah0 = *reinterpret_cast<const bf16x8*>(tbh + (size_t)apix * C + fko);
  bf16x8 ah1 = *reinterpret_cast<const bf16x8*>(tbh + (size_t)apix * C + fko + 32);
  bf16x8 al0 = *reinterpret_cast<const bf16x8*>(tbl + (size_t)apix * C + fko);
  bf16x8 al1 = *reinterpret_cast<const bf16x8*>(tbl + (size_t)apix * C + fko + 32);
  if (!pValid) { ah0 = zf; ah1 = zf; al0 = zf; al1 = zf; }

  const unsigned short* rH = rbh + (size_t)si * HW * C;
  const unsigned short* rL = rbl + (size_t)si * HW * C;

  if (isSearch) {
    int d = gap / 15 + 1; if (d > 4) d = 4;
    const int Zoff = (d == 1) ? 16 : (d == 2) ? 32 : 48;
    const int NZT  = (d == 1) ? 3  : (d == 2) ? 5  : 7;
    const int Minv = (d == 1) ? 65536 : (d == 2) ? 32768 : (d == 3) ? 21846 : 16384;
    const int slot = pz * 4 + wave;             // 0..15
    const int p1 = slot, p2 = slot + 16;
    const float w2 = (p2 <= 24) ? 1.f : 0.f;
    const int row2a = y + d * (p1 - 12);
    const int row2b = y + d * (p2 - 12);
    const bool rva = (row2a >= 0) && (row2a < H);
    const bool rvb = (w2 > 0.f) && (row2b >= 0) && (row2b < H);

    float seA[4] = {0.f, 0.f, 0.f, 0.f};
    float seB[4] = {0.f, 0.f, 0.f, 0.f};
    float sq[4]  = {0.f, 0.f, 0.f, 0.f};

    for (int zt = 0; zt < NZT; ++zt) {
      const int z0 = x0 - Zoff + zt * 16;
      const int z = z0 + fpx;
      const bool zv = (z >= 0) && (z < W);
      const bool bva = rva && zv, bvb = rvb && zv;
      const int bpa = bva ? (row2a * W + z) : 0;
      const int bpb = bvb ? (row2b * W + z) : 0;
      f32x4 accA = band_mfma(ah0, ah1, al0, al1, rH, rL, bpa, fko, bva);
      f32x4 accB = band_mfma(ah0, ah1, al0, al1, rH, rL, bpb, fko, bvb);
#pragma unroll
      for (int r = 0; r < 4; r++) {
        const int xl = (lane >> 4) * 4 + r;
        const int qnum = (z0 + fpx) - (x0 + xl) + 12 * d;
        if (qnum >= 0) {
          const int qq = (qnum * Minv) >> 16;
          if (qq * d == qnum && qq < 25) {
            const float eA = __expf(fminf(accA[r], 60.f));
            const float eB = w2 * __expf(fminf(accB[r], 60.f));
            seA[r] += eA; seB[r] += eB;
            sq[r] += (eA + eB) * (float)(qq - 12);
          }
        }
      }
    }
#pragma unroll
    for (int r = 0; r < 4; r++) {
#pragma unroll
      for (int o = 1; o < 16; o <<= 1) {
        seA[r] += __shfl_xor(seA[r], o, 64);
        seB[r] += __shfl_xor(seB[r], o, 64);
        sq[r]  += __shfl_xor(sq[r],  o, 64);
      }
    }
    if (fpx == 0) {
#pragma unroll
      for (int r = 0; r < 4; r++) {
        const int xl = (lane >> 4) * 4 + r;
        if (x0 + xl < W) {
          float* a = accum + (size_t)(si * HW + y * W + x0 + xl) * 3;
          atomicAdd(a + 0, seA[r] + seB[r]);
          atomicAdd(a + 1, seA[r] * (float)(p1 - 12) + seB[r] * (float)(p2 - 12));
          atomicAdd(a + 2, sq[r]);
        }
      }
    }
  } else {
    const int slot = pz * 4 + wave;             // 0..7
    const int dp1 = slot, dp2 = slot + 8;
    const bool has2 = dp2 < 13;
    const int row2a = y + dp1 - 6;
    const int row2b = y + dp2 - 6;
    const bool rva = (row2a >= 0) && (row2a < H);
    const bool rvb = has2 && (row2b >= 0) && (row2b < H);

    for (int zt = 0; zt < 3; ++zt) {
      const int z0 = x0 - 16 + zt * 16;
      const int z = z0 + fpx;
      const bool zv = (z >= 0) && (z < W);
      const bool bva = rva && zv, bvb = rvb && zv;
      const int bpa = bva ? (row2a * W + z) : 0;
      const int bpb = bvb ? (row2b * W + z) : 0;
      f32x4 accA = band_mfma(ah0, ah1, al0, al1, rH, rL, bpa, fko, bva);
      f32x4 accB = band_mfma(ah0, ah1, al0, al1, rH, rL, bpb, fko, bvb);
#pragma unroll
      for (int r = 0; r < 4; r++) {
        const int xl = (lane >> 4) * 4 + r;
        const int qq = (z0 + fpx) - (x0 + xl) + 6;
        if (qq >= 0 && qq < 13 && (x0 + xl) < W) {
          float* lb = lg + (size_t)(y * W + x0 + xl) * LGS + si * SLG;
          lb[dp1 * 13 + qq] = accA[r];
          if (has2) lb[dp2 * 13 + qq] = accB[r];
        }
      }
    }
  }
}

// Per pixel: offsets -> 14x14 field -> bilinear search logits; unfold logits
// from lg; joint softmax over 507 (+pads); fused bf16 gather.
__global__ __launch_bounds__(256) void k_pix(
    const float* __restrict__ frT, const float* __restrict__ ftT,
    const unsigned short* __restrict__ qrb, const float* __restrict__ lg,
    const float* __restrict__ accum,
    const int* __restrict__ ridx, const int* __restrict__ curp,
    float* __restrict__ out) {
  const int pix = blockIdx.x;
  const int y = pix / W, x = pix - y * W;
  const int tid = threadIdx.x;
  const int lane = tid & 63, wave = tid >> 6;

  __shared__ __align__(16) float tl[64];
  __shared__ float C14[14][16];
  __shared__ float sP[4];
  __shared__ float sLs[4];
  __shared__ __align__(16) float lgs[3 * SLG];
  __shared__ float red[4];
  __shared__ int   wloc[640];
  __shared__ float wval[640];
  __shared__ float part[4][32];

  const int cur = curp[0];
  bool srch[NREF];
  int dd[NREF];
  int ls = -1;
#pragma unroll
  for (int k = 0; k < NREF; k++) {
    const int g = cur - ridx[k];
    srch[k] = (g > 15);
    int d = g / 15 + 1;
    dd[k] = d > 4 ? 4 : d;
    if (srch[k]) ls = k;
  }

  if (tid < 64) tl[tid] = ftT[(size_t)pix * C + tid];
  if (tid < 21) lgs[(tid / 7) * SLG + 169 + (tid % 7)] = -1e30f;   // pads
  __syncthreads();

  // ---- search refs: offsets + field + bilinear logits ----
  for (int si = 0; si < NREF; ++si) {
    if (!srch[si]) continue;
    if (tid == 0) {
      const float* a = accum + (size_t)(si * HW + pix) * 3;
      const float inv = 1.f / a[0];
      const float oy = (float)dd[si] * a[1] * inv, ox = (float)dd[si] * a[2] * inv;
      const float fy = (float)y + oy, fx = (float)x + ox;
      const float Y0 = floorf(fy), X0 = floorf(fx);
      sP[0] = Y0; sP[1] = X0; sP[2] = fy - Y0; sP[3] = fx - X0;
      if (si == ls) { sLs[0] = Y0; sLs[1] = X0; sLs[2] = fy - Y0; sLs[3] = fx - X0; }
    }
    __syncthreads();
    const int iY = (int)sP[0], iX = (int)sP[1];
    const float wy = sP[2], wx = sP[3];
    const float* frB = frT + (size_t)si * HW * C;

    if (tid < 224) {
      const int j = tid >> 4, cg = tid & 15;
      const int col = iX - 6 + j;
      const bool cv = (col >= 0) && (col < W);
      const float4 tv = *reinterpret_cast<const float4*>(&tl[cg * 4]);
#pragma unroll 2
      for (int i = 0; i < 14; ++i) {
        const int row = iY - 6 + i;
        float s = 0.f;
        if (cv && row >= 0 && row < H) {
          const float4 rv4 = *reinterpret_cast<const float4*>(
              frB + (size_t)(row * W + col) * C + cg * 4);
          s = tv.x * rv4.x + tv.y * rv4.y + tv.z * rv4.z + tv.w * rv4.w;
        }
        s += __shfl_xor(s, 1, 64);
        s += __shfl_xor(s, 2, 64);
        s += __shfl_xor(s, 4, 64);
        s += __shfl_xor(s, 8, 64);
        if (cg == 0) C14[i][j] = s;
      }
    }
    __syncthreads();
    for (int it = tid; it < 169; it += 256) {
      const int i = it / 13, j = it - i * 13;
      lgs[si * SLG + it] =
          (1.f - wy) * ((1.f - wx) * C14[i][j] + wx * C14[i][j + 1]) +
          wy * ((1.f - wx) * C14[i + 1][j] + wx * C14[i + 1][j + 1]);
    }
    __syncthreads();   // C14/sP reused by next search ref
  }

  // ---- unfold logits from global (vectorized) ----
  for (int k = 0; k < NREF; k++) {
    if (srch[k]) continue;
    const float* src = lg + (size_t)pix * LGS + k * SLG;
    for (int it = tid; it < 42; it += 256)
      *reinterpret_cast<float4*>(&lgs[k * SLG + it * 4]) =
          *reinterpret_cast<const float4*>(src + it * 4);
    if (tid == 42 * 4 - 168)  // tid==0
      lgs[k * SLG + 168] = src[168];
  }
  __syncthreads();

  // ---- joint softmax over 507 (+ -1e30 pads) ----
  float m = -1e30f;
  for (int i = tid; i < 3 * SLG; i += 256) m = fmaxf(m, lgs[i]);
  m = block_max(m, red);
  float se = 0.f;
  for (int i = tid; i < 3 * SLG; i += 256) {
    const float e = __expf(lgs[i] - m);
    lgs[i] = e;
    se += e;
  }
  se = block_sum(se, red);
  const float inv = 1.f / se;

  // ---- build gather list (compact) ----
  int bases[NREF], tot = 0;
#pragma unroll
  for (int k = 0; k < NREF; k++) { bases[k] = tot; tot += srch[k] ? 196 : 169; }
  const int NT = (tot + 63) >> 6;

  int liY = 0, liX = 0; float lwy = 0.f, lwx = 0.f;
  if (ls >= 0) { liY = (int)sLs[0]; liX = (int)sLs[1]; lwy = sLs[2]; lwx = sLs[3]; }

  for (int k = 0; k < NREF; k++) {
    const int base = bases[k];
    if (srch[k]) {
      const float* wk = &lgs[k * SLG];
      for (int it = tid; it < 196; it += 256) {
        const int i = it / 14, j = it - i * 14;
        const float a00 = (i < 13 && j < 13) ? wk[i * 13 + j] : 0.f;
        const float a01 = (i < 13 && j >= 1) ? wk[i * 13 + j - 1] : 0.f;
        const float a10 = (i >= 1 && j < 13) ? wk[(i - 1) * 13 + j] : 0.f;
        const float a11 = (i >= 1 && j >= 1) ? wk[(i - 1) * 13 + j - 1] : 0.f;
        const float wv = (1.f - lwy) * ((1.f - lwx) * a00 + lwx * a01) +
                         lwy * ((1.f - lwx) * a10 + lwx * a11);
        const int row = liY + i - 6, col = liX + j - 6;
        const bool v = (unsigned)row < (unsigned)H && (unsigned)col < (unsigned)W;
        wloc[base + it] = v ? (k * HW + row * W + col) : 0;
        wval[base + it] = v ? wv : 0.f;
      }
    } else {
      for (int it = tid; it < 169; it += 256) {
        const int p = it / 13, q = it - p * 13;
        const int row = y + p - 6, col = x + q - 6;
        const bool v = (unsigned)row < (unsigned)H && (unsigned)col < (unsigned)W;
        wloc[base + it] = v ? (k * HW + row * W + col) : 0;
        wval[base + it] = v ? lgs[k * SLG + it] : 0.f;
      }
    }
  }
  for (int e = tot + tid; e < NT * 64; e += 256) { wloc[e] = 0; wval[e] = 0.f; }
  __syncthreads();

  // ---- gather: 4 lanes per location, bf16x8 channels per lane ----
  const int c4 = lane & 3, l16 = lane >> 2;
  float a[8] = {0.f, 0.f, 0.f, 0.f, 0.f, 0.f, 0.f, 0.f};
  for (int t = 0; t < NT; ++t) {
    const int e = t * 64 + wave * 16 + l16;
    const float wv = wval[e];
    const int loc = wloc[e];
    const bf16x8 qv = *reinterpret_cast<const bf16x8*>(
        qrb + (size_t)loc * CQ + c4 * 8);
#pragma unroll
    for (int j = 0; j < 8; j++)
      a[j] = fmaf(wv, bf2f((unsigned short)qv[j]), a[j]);
  }
#pragma unroll
  for (int o = 4; o < 64; o <<= 1) {
#pragma unroll
    for (int j = 0; j < 8; j++) a[j] += __shfl_xor(a[j], o, 64);
  }
  if (l16 == 0) {
#pragma unroll
    for (int j = 0; j < 8; j++) part[wave][c4 * 8 + j] = a[j];
  }
  __syncthreads();
  if (tid < 32) {
    const float s = part[0][tid] + part[1][tid] + part[2][tid] + part[3][tid];
    out[(size_t)tid * HW + pix] = s * inv;
  }
}

extern "C" void kernel_launch(void* const* d_in, const int* in_sizes, int n_in,
                              void* d_out, int out_size, void* d_ws, size_t ws_size,
                              hipStream_t stream) {
  (void)in_sizes; (void)n_in; (void)out_size; (void)ws_size;
  const float* fr = (const float*)d_in[0];   // feats_r      (3,1,64,48,84)
  const float* ft = (const float*)d_in[1];   // feats_t      (1,64,48,84)
  const float* q  = (const float*)d_in[2];   // quantized_r  (3,1,32,192,336)
  const int* ridx = (const int*)d_in[3];     // ref_index    (3,)
  const int* cur  = (const int*)d_in[4];     // current_ind  (1,)
  float* out = (float*)d_out;

  char* ws = (char*)d_ws;
  float* frT  = (float*)ws;                   ws += (size_t)NREF * HW * C * 4;
  float* ftT  = (float*)ws;                   ws += (size_t)HW * C * 4;
  unsigned short* rbh = (unsigned short*)ws;  ws += (size_t)NREF * HW * C * 2;
  unsigned short* rbl = (unsigned short*)ws;  ws += (size_t)NREF * HW * C * 2;
  unsigned short* tbh = (unsigned short*)ws;  ws += (size_t)HW * C * 2;
  unsigned short* tbl = (unsigned short*)ws;  ws += (size_t)HW * C * 2;
  unsigned short* qrb = (unsigned short*)ws;  ws += (size_t)NREF * HW * CQ * 2;
  float* lg    = (float*)ws;                  ws += (size_t)HW * LGS * 4;
  float* accum = (float*)ws;                  ws += (size_t)NREF * HW * 3 * 4;

  k_prep<<<dim3(HW / 64, 8), dim3(256), 0, stream>>>(fr, ft, q, frT, ftT,
                                                     rbh, rbl, tbh, tbl, qrb, accum);
  k_mfma<<<dim3(8 * 432), dim3(256), 0, stream>>>(rbh, rbl, tbh, tbl,
                                                  ridx, cur, accum, lg);
  k_pix<<<dim3(HW), dim3(256), 0, stream>>>(frT, ftT, qrb, lg, accum,
                                            ridx, cur, out);
}

// Round 6
// 80.959 us; speedup vs baseline: 1.0742x; 1.0742x over previous
//
#include <hip/hip_runtime.h>
#include <math.h>

constexpr int H  = 48;
constexpr int W  = 84;
constexpr int HW = H * W;      // 4032
constexpr int C  = 64;
constexpr int CQ = 32;
constexpr int QH = 192;
constexpr int QW = 336;
constexpr int NREF = 3;
constexpr int SLG = 176;       // per-ref unfold logit stride (16B aligned)
constexpr int LGS = 544;       // per-pixel unfold stride = 3*176 + 16
constexpr int S625 = 640;      // per-pixel search logit stride

// zero-row indexing for the packed bf16 hi/lo feature buffers
constexpr int RROWS = NREF * HW;   // hi rows in rb
constexpr int RZERO = RROWS;       // zero hi row
constexpr int RLO   = RROWS + 1;   // lo rows base (lo zero row at RLO+RROWS)
constexpr int TZERO = HW;
constexpr int TLO   = HW + 1;

typedef short bf16x8 __attribute__((ext_vector_type(8)));
typedef float f32x4  __attribute__((ext_vector_type(4)));

#define DEV __device__ __forceinline__

DEV unsigned short f2bf_rn(float f) {
  unsigned int u = __builtin_bit_cast(unsigned int, f);
  u += 0x7FFFu + ((u >> 16) & 1u);
  return (unsigned short)(u >> 16);
}
DEV float bf2f(unsigned short h) {
  unsigned int u = ((unsigned int)h) << 16;
  return __builtin_bit_cast(float, u);
}

DEV float block_sum(float v, float* red) {
  __syncthreads();
#pragma unroll
  for (int o = 32; o > 0; o >>= 1) v += __shfl_down(v, o, 64);
  if ((threadIdx.x & 63) == 0) red[threadIdx.x >> 6] = v;
  __syncthreads();
  return red[0] + red[1] + red[2] + red[3];
}
DEV float block_max(float v, float* red) {
  __syncthreads();
#pragma unroll
  for (int o = 32; o > 0; o >>= 1) v = fmaxf(v, __shfl_down(v, o, 64));
  if ((threadIdx.x & 63) == 0) red[threadIdx.x >> 6] = v;
  __syncthreads();
  return fmaxf(fmaxf(red[0], red[1]), fmaxf(red[2], red[3]));
}

// mode<4: transpose feats to channel-last (fp32 + split-bf16 into rb/tb with
//         zero rows). mode 4..6: gather quantized_r[:, :, ::4, ::4] -> bf16.
__global__ __launch_bounds__(256) void k_prep(const float* __restrict__ fr,
                                              const float* __restrict__ ft,
                                              const float* __restrict__ q,
                                              float* __restrict__ frT,
                                              float* __restrict__ ftT,
                                              unsigned short* __restrict__ rb,
                                              unsigned short* __restrict__ tb,
                                              unsigned short* __restrict__ qrb) {
  __shared__ float lds[64][65];
  const int mode = blockIdx.y;
  const int tid = threadIdx.x;

  if (mode < 4) {
    const int r = mode;
    const float* src = (r < NREF) ? (fr + (size_t)r * C * HW) : ft;
    float* dstF          = (r < NREF) ? (frT + (size_t)r * HW * C) : ftT;
    unsigned short* dstH = (r < NREF) ? (rb + (size_t)r * HW * C) : tb;
    const size_t loOff   = (size_t)((r < NREF) ? RLO : TLO) * C;
    const int pb = blockIdx.x * 64;
    const int a = tid & 63, b = tid >> 6;
#pragma unroll
    for (int i = 0; i < 16; i++) {
      int c = i * 4 + b;
      lds[c][a] = src[c * HW + pb + a];
    }
    __syncthreads();
#pragma unroll
    for (int i = 0; i < 16; i++) {
      int p = i * 4 + b;
      float v = lds[a][p];
      size_t o = (size_t)(pb + p) * C + a;
      dstF[o] = v;
      unsigned short h = f2bf_rn(v);
      dstH[o] = h;
      dstH[o + loOff] = f2bf_rn(v - bf2f(h));
    }
    if (mode == 3 && blockIdx.x == 0 && tid < 64) {
      rb[(size_t)RZERO * C + tid] = 0;
      rb[(size_t)(RLO + RROWS) * C + tid] = 0;
      tb[(size_t)TZERO * C + tid] = 0;
      tb[(size_t)(TLO + HW) * C + tid] = 0;
    }
  } else {
    const int k = mode - 4;
    const int yq = blockIdx.x;
    if (yq >= H) return;
    unsigned short* qs = (unsigned short*)lds;   // [x][c]
    const int c = tid >> 3, xo = tid & 7;
#pragma unroll
    for (int i = 0; i < 11; i++) {
      const int x = xo + 8 * i;
      if (x < W) {
        const float v = q[((size_t)(k * CQ + c) * QH + yq * 4) * QW + x * 4];
        qs[x * CQ + c] = f2bf_rn(v);
      }
    }
    __syncthreads();
    const unsigned int* qsu = (const unsigned int*)qs;
    unsigned int* dst = (unsigned int*)(qrb + (size_t)k * HW * CQ + (size_t)yq * W * CQ);
    for (int o = tid; o < W * CQ / 2; o += 256) dst[o] = qsu[o];
  }
}

// Banded MFMA correlations -> RAW logit stores (no exp, no reduce, no atomics).
// z = si*7+pz, wave -> band row (search p in 0..24, unfold dp in 0..12).
// Double-buffered B prefetch; OOB handled by zero-row index redirection.
__global__ __launch_bounds__(256) void k_mfma(
    const unsigned short* __restrict__ rb, const unsigned short* __restrict__ tb,
    const int* __restrict__ ridx, const int* __restrict__ curp,
    float* __restrict__ lg, float* __restrict__ lg625) {
  const int si = blockIdx.z / 7, pz = blockIdx.z % 7;
  const int gap = curp[0] - ridx[si];
  const bool isSearch = gap > 15;
  const int lane = threadIdx.x & 63, wave = threadIdx.x >> 6;
  const int sub = pz * 4 + wave;
  if (isSearch ? (sub >= 25) : (sub >= 13)) return;

  const int y = blockIdx.y, x0 = blockIdx.x * 16;
  const int fpx = lane & 15, fko = (lane >> 4) * 8;

  // A fragments (zero-row redirect for x >= W)
  const int gapix = (x0 + fpx < W) ? (y * W + x0 + fpx) : TZERO;
  const unsigned short* tbb = tb + (size_t)gapix * C + fko;
  const bf16x8 ah0 = *reinterpret_cast<const bf16x8*>(tbb);
  const bf16x8 ah1 = *reinterpret_cast<const bf16x8*>(tbb + 32);
  const bf16x8 al0 = *reinterpret_cast<const bf16x8*>(tbb + (size_t)TLO * C);
  const bf16x8 al1 = *reinterpret_cast<const bf16x8*>(tbb + (size_t)TLO * C + 32);

  int d = 1, Zoff = 16, NZT = 3, Minv = 65536, qoff = 6, qmax = 13;
  if (isSearch) {
    d = gap / 15 + 1; if (d > 4) d = 4;
    Zoff = (d == 1) ? 16 : (d == 2) ? 32 : 48;
    NZT  = (d == 1) ? 3  : (d == 2) ? 5  : 7;
    Minv = (d == 1) ? 65536 : (d == 2) ? 32768 : (d == 3) ? 21846 : 16384;
    qoff = 12 * d; qmax = 25;
  }
  const int row2 = isSearch ? (y + d * (sub - 12)) : (y + sub - 6);
  const bool rv = (row2 >= 0) && (row2 < H);
  const int rowoff = si * HW + row2 * W;

  // per-pixel store bases
  float* sb[4];
#pragma unroll
  for (int r = 0; r < 4; r++) {
    const int xl = (lane >> 4) * 4 + r;
    sb[r] = isSearch
        ? (lg625 + ((size_t)si * HW + y * W + x0 + xl) * S625 + sub * 25)
        : (lg + (size_t)(y * W + x0 + xl) * LGS + si * SLG + sub * 13);
  }

  auto gofs = [&](int zt) -> size_t {
    const int z = x0 - Zoff + zt * 16 + fpx;
    const bool v = rv && (z >= 0) && (z < W);
    const int gp = v ? (rowoff + z) : RZERO;
    return (size_t)gp * C + fko;
  };

  size_t o = gofs(0);
  bf16x8 nh0 = *reinterpret_cast<const bf16x8*>(rb + o);
  bf16x8 nh1 = *reinterpret_cast<const bf16x8*>(rb + o + 32);
  bf16x8 nl0 = *reinterpret_cast<const bf16x8*>(rb + o + (size_t)RLO * C);
  bf16x8 nl1 = *reinterpret_cast<const bf16x8*>(rb + o + (size_t)RLO * C + 32);

  for (int zt = 0; zt < NZT; ++zt) {
    const bf16x8 bh0 = nh0, bh1 = nh1, bl0 = nl0, bl1 = nl1;
    if (zt + 1 < NZT) {
      o = gofs(zt + 1);
      nh0 = *reinterpret_cast<const bf16x8*>(rb + o);
      nh1 = *reinterpret_cast<const bf16x8*>(rb + o + 32);
      nl0 = *reinterpret_cast<const bf16x8*>(rb + o + (size_t)RLO * C);
      nl1 = *reinterpret_cast<const bf16x8*>(rb + o + (size_t)RLO * C + 32);
    }
    f32x4 acc = {0.f, 0.f, 0.f, 0.f};
    acc = __builtin_amdgcn_mfma_f32_16x16x32_bf16(ah0, bh0, acc, 0, 0, 0);
    acc = __builtin_amdgcn_mfma_f32_16x16x32_bf16(ah1, bh1, acc, 0, 0, 0);
    acc = __builtin_amdgcn_mfma_f32_16x16x32_bf16(ah0, bl0, acc, 0, 0, 0);
    acc = __builtin_amdgcn_mfma_f32_16x16x32_bf16(ah1, bl1, acc, 0, 0, 0);
    acc = __builtin_amdgcn_mfma_f32_16x16x32_bf16(al0, bh0, acc, 0, 0, 0);
    acc = __builtin_amdgcn_mfma_f32_16x16x32_bf16(al1, bh1, acc, 0, 0, 0);

    const int zbase = x0 - Zoff + zt * 16 + fpx - x0 + qoff;  // qnum - xl
#pragma unroll
    for (int r = 0; r < 4; r++) {
      const int xl = (lane >> 4) * 4 + r;
      const int qnum = zbase - xl;
      if (qnum >= 0) {
        const int qq = (qnum * Minv) >> 16;
        if (qq * d == qnum && qq < qmax && (x0 + xl) < W) sb[r][qq] = acc[r];
      }
    }
  }
}

// Per pixel: 625-softmax -> offsets -> 14x14 field -> bilinear logits;
// unfold logits; joint softmax over 507; fused bf16 gather.
__global__ __launch_bounds__(256) void k_pix(
    const float* __restrict__ frT, const float* __restrict__ ftT,
    const unsigned short* __restrict__ qrb, const float* __restrict__ lg,
    const float* __restrict__ lg625,
    const int* __restrict__ ridx, const int* __restrict__ curp,
    float* __restrict__ out) {
  const int pix = blockIdx.x;
  const int y = pix / W, x = pix - y * W;
  const int tid = threadIdx.x;
  const int lane = tid & 63, wave = tid >> 6;

  __shared__ __align__(16) float tl[64];
  __shared__ float C14[14][16];
  __shared__ float sP[4];
  __shared__ float sLs[4];
  __shared__ __align__(16) float lgs[3 * SLG];
  __shared__ __align__(16) float ls6[S625];
  __shared__ float red[4];
  __shared__ int   wloc[640];
  __shared__ float wval[640];
  __shared__ float part[4][32];

  const int cur = curp[0];
  bool srch[NREF];
  int dd[NREF];
  int ls = -1;
#pragma unroll
  for (int k = 0; k < NREF; k++) {
    const int g = cur - ridx[k];
    srch[k] = (g > 15);
    int d = g / 15 + 1;
    dd[k] = d > 4 ? 4 : d;
    if (srch[k]) ls = k;
  }

  if (tid < 64) tl[tid] = ftT[(size_t)pix * C + tid];
  if (tid < 21) lgs[(tid / 7) * SLG + 169 + (tid % 7)] = -1e30f;   // pads

  // ---- search refs: 625-softmax offsets + field + bilinear logits ----
  for (int si = 0; si < NREF; ++si) {
    if (!srch[si]) continue;
    const float* Lp = lg625 + ((size_t)si * HW + pix) * S625;
    __syncthreads();   // protect ls6 reuse
    if (tid < 156)
      *reinterpret_cast<float4*>(&ls6[tid * 4]) =
          *reinterpret_cast<const float4*>(Lp + tid * 4);
    else if (tid == 156) ls6[624] = Lp[624];
    else if (tid < 172) ls6[624 + tid - 156] = -1e30f;   // pads 625..639

    float m = -1e30f;
    for (int i = tid; i < S625; i += 256) m = fmaxf(m, ls6[i]);
    m = block_max(m, red);
    float se = 0.f, sy = 0.f, sx = 0.f;
    for (int i = tid; i < S625; i += 256) {
      const float e = __expf(ls6[i] - m);
      const int p = (i * 5243) >> 17;      // i/25 for i<3277
      const int q = i - p * 25;
      se += e; sy += e * (float)(p - 12); sx += e * (float)(q - 12);
    }
    se = block_sum(se, red);
    sy = block_sum(sy, red);
    sx = block_sum(sx, red);
    if (tid == 0) {
      const float inv = 1.f / se;
      const float oy = (float)dd[si] * sy * inv, ox = (float)dd[si] * sx * inv;
      const float fy = (float)y + oy, fx = (float)x + ox;
      const float Y0 = floorf(fy), X0 = floorf(fx);
      sP[0] = Y0; sP[1] = X0; sP[2] = fy - Y0; sP[3] = fx - X0;
      if (si == ls) { sLs[0] = Y0; sLs[1] = X0; sLs[2] = fy - Y0; sLs[3] = fx - X0; }
    }
    __syncthreads();
    const int iY = (int)sP[0], iX = (int)sP[1];
    const float wy = sP[2], wx = sP[3];
    const float* frB = frT + (size_t)si * HW * C;

    if (tid < 224) {
      const int j = tid >> 4, cg = tid & 15;
      const int col = iX - 6 + j;
      const bool cv = (col >= 0) && (col < W);
      const float4 tv = *reinterpret_cast<const float4*>(&tl[cg * 4]);
      float s[14];
#pragma unroll
      for (int i = 0; i < 14; ++i) {
        const int row = iY - 6 + i;
        s[i] = 0.f;
        if (cv && row >= 0 && row < H) {
          const float4 rv4 = *reinterpret_cast<const float4*>(
              frB + (size_t)(row * W + col) * C + cg * 4);
          s[i] = tv.x * rv4.x + tv.y * rv4.y + tv.z * rv4.z + tv.w * rv4.w;
        }
      }
#pragma unroll
      for (int i = 0; i < 14; ++i) {
        s[i] += __shfl_xor(s[i], 1, 64);
        s[i] += __shfl_xor(s[i], 2, 64);
        s[i] += __shfl_xor(s[i], 4, 64);
        s[i] += __shfl_xor(s[i], 8, 64);
      }
      if (cg == 0) {
#pragma unroll
        for (int i = 0; i < 14; ++i) C14[i][j] = s[i];
      }
    }
    __syncthreads();
    for (int it = tid; it < 169; it += 256) {
      const int i = it / 13, j = it - i * 13;
      lgs[si * SLG + it] =
          (1.f - wy) * ((1.f - wx) * C14[i][j] + wx * C14[i][j + 1]) +
          wy * ((1.f - wx) * C14[i + 1][j] + wx * C14[i + 1][j + 1]);
    }
  }

  // ---- unfold logits from global (vectorized) ----
  for (int k = 0; k < NREF; k++) {
    if (srch[k]) continue;
    const float* src = lg + (size_t)pix * LGS + k * SLG;
    for (int it = tid; it < 42; it += 256)
      *reinterpret_cast<float4*>(&lgs[k * SLG + it * 4]) =
          *reinterpret_cast<const float4*>(src + it * 4);
    if (tid == 42) lgs[k * SLG + 168] = src[168];
  }
  __syncthreads();

  // ---- joint softmax over 507 (+ -1e30 pads) ----
  float m = -1e30f;
  for (int i = tid; i < 3 * SLG; i += 256) m = fmaxf(m, lgs[i]);
  m = block_max(m, red);
  float se = 0.f;
  for (int i = tid; i < 3 * SLG; i += 256) {
    const float e = __expf(lgs[i] - m);
    lgs[i] = e;
    se += e;
  }
  se = block_sum(se, red);
  const float inv = 1.f / se;

  // ---- build gather list (compact) ----
  int bases[NREF], tot = 0;
#pragma unroll
  for (int k = 0; k < NREF; k++) { bases[k] = tot; tot += srch[k] ? 196 : 169; }
  const int NT = (tot + 63) >> 6;

  int liY = 0, liX = 0; float lwy = 0.f, lwx = 0.f;
  if (ls >= 0) { liY = (int)sLs[0]; liX = (int)sLs[1]; lwy = sLs[2]; lwx = sLs[3]; }

  for (int k = 0; k < NREF; k++) {
    const int base = bases[k];
    if (srch[k]) {
      const float* wk = &lgs[k * SLG];
      for (int it = tid; it < 196; it += 256) {
        const int i = it / 14, j = it - i * 14;
        const float a00 = (i < 13 && j < 13) ? wk[i * 13 + j] : 0.f;
        const float a01 = (i < 13 && j >= 1) ? wk[i * 13 + j - 1] : 0.f;
        const float a10 = (i >= 1 && j < 13) ? wk[(i - 1) * 13 + j] : 0.f;
        const float a11 = (i >= 1 && j >= 1) ? wk[(i - 1) * 13 + j - 1] : 0.f;
        const float wv = (1.f - lwy) * ((1.f - lwx) * a00 + lwx * a01) +
                         lwy * ((1.f - lwx) * a10 + lwx * a11);
        const int row = liY + i - 6, col = liX + j - 6;
        const bool v = (unsigned)row < (unsigned)H && (unsigned)col < (unsigned)W;
        wloc[base + it] = v ? (k * HW + row * W + col) : 0;
        wval[base + it] = v ? wv : 0.f;
      }
    } else {
      for (int it = tid; it < 169; it += 256) {
        const int p = it / 13, q = it - p * 13;
        const int row = y + p - 6, col = x + q - 6;
        const bool v = (unsigned)row < (unsigned)H && (unsigned)col < (unsigned)W;
        wloc[base + it] = v ? (k * HW + row * W + col) : 0;
        wval[base + it] = v ? lgs[k * SLG + it] : 0.f;
      }
    }
  }
  for (int e = tot + tid; e < NT * 64; e += 256) { wloc[e] = 0; wval[e] = 0.f; }
  __syncthreads();

  // ---- gather: 4 lanes per location, bf16x8 channels per lane ----
  const int c4 = lane & 3, l16 = lane >> 2;
  float a[8] = {0.f, 0.f, 0.f, 0.f, 0.f, 0.f, 0.f, 0.f};
  for (int t = 0; t < NT; ++t) {
    const int e = t * 64 + wave * 16 + l16;
    const float wv = wval[e];
    const int loc = wloc[e];
    const bf16x8 qv = *reinterpret_cast<const bf16x8*>(
        qrb + (size_t)loc * CQ + c4 * 8);
#pragma unroll
    for (int j = 0; j < 8; j++)
      a[j] = fmaf(wv, bf2f((unsigned short)qv[j]), a[j]);
  }
#pragma unroll
  for (int o = 4; o < 64; o <<= 1) {
#pragma unroll
    for (int j = 0; j < 8; j++) a[j] += __shfl_xor(a[j], o, 64);
  }
  if (l16 == 0) {
#pragma unroll
    for (int j = 0; j < 8; j++) part[wave][c4 * 8 + j] = a[j];
  }
  __syncthreads();
  if (tid < 32) {
    const float s = part[0][tid] + part[1][tid] + part[2][tid] + part[3][tid];
    out[(size_t)tid * HW + pix] = s * inv;
  }
}

extern "C" void kernel_launch(void* const* d_in, const int* in_sizes, int n_in,
                              void* d_out, int out_size, void* d_ws, size_t ws_size,
                              hipStream_t stream) {
  (void)in_sizes; (void)n_in; (void)out_size; (void)ws_size;
  const float* fr = (const float*)d_in[0];   // feats_r      (3,1,64,48,84)
  const float* ft = (const float*)d_in[1];   // feats_t      (1,64,48,84)
  const float* q  = (const float*)d_in[2];   // quantized_r  (3,1,32,192,336)
  const int* ridx = (const int*)d_in[3];     // ref_index    (3,)
  const int* cur  = (const int*)d_in[4];     // current_ind  (1,)
  float* out = (float*)d_out;

  char* ws = (char*)d_ws;
  float* frT  = (float*)ws;                  ws += (size_t)NREF * HW * C * 4;
  float* ftT  = (float*)ws;                  ws += (size_t)HW * C * 4;
  unsigned short* rb = (unsigned short*)ws;  ws += (size_t)2 * (NREF * HW + 1) * C * 2;
  unsigned short* tb = (unsigned short*)ws;  ws += (size_t)2 * (HW + 1) * C * 2;
  unsigned short* qrb = (unsigned short*)ws; ws += (size_t)NREF * HW * CQ * 2;
  float* lg    = (float*)ws;                 ws += (size_t)HW * LGS * 4;
  float* lg625 = (float*)ws;                 ws += (size_t)NREF * HW * S625 * 4;

  k_prep<<<dim3(HW / 64, 7), dim3(256), 0, stream>>>(fr, ft, q, frT, ftT,
                                                     rb, tb, qrb);
  k_mfma<<<dim3(6, H, NREF * 7), dim3(256), 0, stream>>>(rb, tb, ridx, cur,
                                                         lg, lg625);
  k_pix<<<dim3(HW), dim3(256), 0, stream>>>(frT, ftT, qrb, lg, lg625,
                                            ridx, cur, out);
}